// Round 21
// baseline (121.370 us; speedup 1.0000x reference)
//
#include <hip/hip_runtime.h>
#include <math.h>

constexpr int B = 2, C = 16, H = 128, W = 128;
constexpr int HW = H * W;

// xpad: [B,16,146,148]; orig (h,w) -> (h+9, w+9); pads zeroed by conv1
constexpr int XR = 146, XS = 148, XCH = XR * XS;
constexpr size_t XPAD_ELEMS = (size_t)B * C * XCH;

// ypad: [B,16,130,136]; orig (h,w) -> (h+1, w+4); pads zeroed by kpn19
constexpr int YR = 130, YS = 136, YCH = YR * YS;

__device__ __forceinline__ float4 ld4(const float* p) { return *(const float4*)p; }

// ===========================================================================
// kpn19: r16 skeleton (q-split, gll x-staging, vmcnt(0)+sync per row, kern on
// demand-VMEM path) with register-window compute:
// thread = 4 px (pq*4) x 1 ch; per row: 6 ds_read_b128 pull the 24-float x
// window into regs (vs r16's 76 ds_read_b32 -> 12x fewer LDS instrs, 3.2x
// less LDS data), kern = 19 float4 demand loads in 4-wide batches (16 VGPR
// per batch keeps total demand ~60 < the 64 budget -> no sink/spill).
// Block = 4q x (16pq x 16ch) = 1024 thr; grid = wb2 x h128 x b2 = 512
// (2 blocks/CU by LDS, 32 waves/CU).
// ===========================================================================
#define XC(A, I)                                                             \
  (((I) & 3) == 0 ? A[(I) >> 2].x : ((I) & 3) == 1 ? A[(I) >> 2].y           \
   : ((I) & 3) == 2 ? A[(I) >> 2].z : A[(I) >> 2].w)

__global__ __launch_bounds__(1024) void kpn19(
    const float* __restrict__ xpad,  // [B,16,146,148]
    const float* __restrict__ kern,  // [B,361,128,128]
    float* __restrict__ ypad)        // [B,16,130,136]
{
    __shared__ __align__(16) float xls[4][2][16][84];   // 43,008 B
    __shared__ __align__(16) float red[3][16][64];      // 12,288 B

    int tid  = threadIdx.x;
    int lane = tid & 63;
    int wq   = (tid >> 6) & 3;       // wave within q-group (uniform)
    int q    = tid >> 8;             // kh-quarter (uniform)
    int idx  = tid & 255;
    int pq   = idx & 15;             // px quad: px0 = w0 + pq*4
    int ch   = idx >> 4;             // channel 0..15
    int blk  = blockIdx.x;           // 512 = wb2 x h128 x b2
    int wb   = blk & 1;
    int h    = (blk >> 1) & 127;
    int b    = blk >> 8;
    int w0   = wb * 64;

    // ---- ypad pad zeroing (replaces memset) ----
    if (tid < 64) {
        int pl = tid >> 2, i = tid & 3;
        int col = wb ? 132 + i : i;
        ypad[((size_t)(b * C + pl) * YR + (h + 1)) * YS + col] = 0.f;
    }
    if (h == 0 || h == 127) {
        int r = (h == 0) ? 0 : 129;
        for (int f = tid; f < 1088; f += 1024) {
            int pl = f / 68, col = wb * 68 + f % 68;
            ypad[((size_t)(b * C + pl) * YR + r) * YS + col] = 0.f;
        }
    }

    // ---- x staging sources (r16-verbatim): 336 chunks = [16 ch][21 col4] ----
    int ma  = idx;
    int mb  = idx + 256;
    bool vb = (mb < 336);
    int ca  = ma / 21, cola = ma % 21;
    int cb  = vb ? mb / 21 : 0, colb = vb ? mb % 21 : 0;
    int kh0 = q * 5;
    int nkh = (q == 3) ? 4 : 5;

    const float* sa = xpad + (size_t)(b * C + ca) * XCH
                      + (size_t)(h + kh0) * XS + w0 + cola * 4;
    const float* sb = xpad + (size_t)(b * C + cb) * XCH
                      + (size_t)(h + kh0) * XS + w0 + colb * 4;

    const float* kp4 = kern + (size_t)b * 361 * HW + (size_t)h * W + w0 + pq * 4;

    float4 acc = make_float4(0.f, 0.f, 0.f, 0.f);

#define STAGE(bufsel)                                                         \
    {                                                                         \
        __builtin_amdgcn_global_load_lds((const void*)sa,                     \
            (void*)(&xls[q][bufsel][0][0] + wq * 256), 16, 0, 0);             \
        if (vb)                                                               \
            __builtin_amdgcn_global_load_lds((const void*)sb,                 \
                (void*)(&xls[q][bufsel][0][0] + 1024 + wq * 256), 16, 0, 0);  \
        sa += XS; sb += XS;                                                   \
    }

    STAGE(0);
    asm volatile("s_waitcnt vmcnt(0)" ::: "memory");
    __syncthreads();

    #pragma unroll
    for (int r = 0; r < 5; ++r) {
        const int cur = r & 1;
        if (r + 1 < nkh) STAGE(cur ^ 1);          // overlaps compute
        if (r < nkh) {
            int kh = kh0 + r;
            const float* kpr = kp4 + (size_t)(kh * 19) * HW;
            // x window -> registers: 6 wide LDS reads (16B aligned)
            const float* xb_ = &xls[q][cur][ch][pq * 4];
            float4 xw[6];
            #pragma unroll
            for (int t = 0; t < 6; ++t) xw[t] = ld4(xb_ + 4 * t);
            // kern: 19 float4 demand loads in 4-wide batches
            #pragma unroll
            for (int kb = 0; kb < 5; ++kb) {
                const int nk = (kb == 4) ? 3 : 4;
                float4 kv4[4];
                #pragma unroll
                for (int j = 0; j < 4; ++j)
                    if (j < nk) kv4[j] = ld4(kpr + (size_t)(kb * 4 + j) * HW);
                __builtin_amdgcn_sched_barrier(0);
                #pragma unroll
                for (int j = 0; j < 4; ++j)
                    if (j < nk) {
                        const int kw = kb * 4 + j;
                        float4 kq = kv4[j];
                        acc.x = fmaf(XC(xw, kw + 0), kq.x, acc.x);
                        acc.y = fmaf(XC(xw, kw + 1), kq.y, acc.y);
                        acc.z = fmaf(XC(xw, kw + 2), kq.z, acc.z);
                        acc.w = fmaf(XC(xw, kw + 3), kq.w, acc.w);
                    }
            }
        }
        asm volatile("s_waitcnt vmcnt(0)" ::: "memory");
        __syncthreads();
    }
#undef STAGE

    // ---- reduce quarters via LDS (float4); q0 writes y ----
    if (q > 0) *(float4*)&red[q - 1][ch][pq * 4] = acc;
    __syncthreads();
    if (q == 0) {
        #pragma unroll
        for (int j = 0; j < 3; ++j) {
            float4 rv = ld4(&red[j][ch][pq * 4]);
            acc.x += rv.x; acc.y += rv.y; acc.z += rv.z; acc.w += rv.w;
        }
        float* yp = ypad + ((size_t)(b * C + ch) * YR + (h + 1)) * YS + (w0 + pq * 4 + 4);
        *(float4*)yp = acc;
    }
}

// ===========================================================================
// conv1 (FROZEN r20): one block per (h,b), LDS tile staged once,
// per-ic ds_read batch + 36 FMA, #pragma unroll 1 (spill-free).
// ===========================================================================
__global__ __launch_bounds__(512) void conv1_gelu(
    const float* __restrict__ in, const float* __restrict__ w1,
    const float* __restrict__ b1, float* __restrict__ xpad)
{
    __shared__ float ws[2304];
    __shared__ float bs[16];
    __shared__ __align__(16) float xs[16][3][128];   // 24 KB

    int tid = threadIdx.x;
    for (int i = tid; i < 2304; i += 512) ws[i] = w1[i];
    if (tid < 16) bs[tid] = b1[tid];

    int px  = tid & 127;
    int ocg = tid >> 7;                  // 0..3, wave-uniform
    int blk = blockIdx.x;                // 256 = h128 x b2
    int h   = blk & 127;
    int b   = blk >> 7;
    int oc0 = ocg * 4;

    if (tid < 320) {
        int j = tid / 20, i = tid % 20;
        int col = (i < 9) ? i : 128 + i;
        xpad[((size_t)(b * C + j) * XR + (h + 9)) * XS + col] = 0.f;
    }
    if (h == 0 || h == 127) {
        int r0 = (h == 0) ? 0 : 137;
        for (int f = tid; f < 16 * 9 * XS; f += 512) {
            int j = f / (9 * XS), rem = f % (9 * XS);
            int r = r0 + rem / XS, col = rem % XS;
            xpad[((size_t)(b * C + j) * XR + r) * XS + col] = 0.f;
        }
    }

    const float4 z4 = make_float4(0.f, 0.f, 0.f, 0.f);
    #pragma unroll
    for (int j = 0; j < 3; ++j) {
        int m = tid + j * 512;           // < 1536 exactly
        int ic = m / 96, rem = m - ic * 96, r = rem >> 5, qq = rem & 31;
        int row = h + r - 1;
        float4 v = ((unsigned)row < 128u)
                 ? ld4(in + ((size_t)(b * C + ic) * H + row) * W + qq * 4) : z4;
        *(float4*)&xs[ic][r][qq * 4] = v;
    }
    __syncthreads();

    bool wm = (px > 0), wp = (px < 127);
    float a0 = 0.f, a1 = 0.f, a2 = 0.f, a3 = 0.f;

    #pragma unroll 1
    for (int ic = 0; ic < 16; ++ic) {
        float t[9];
        #pragma unroll
        for (int r = 0; r < 3; ++r) {
            t[r * 3 + 0] = wm ? xs[ic][r][px - 1] : 0.f;
            t[r * 3 + 1] = xs[ic][r][px];
            t[r * 3 + 2] = wp ? xs[ic][r][px + 1] : 0.f;
        }
        #pragma unroll
        for (int j = 0; j < 4; ++j) {
            const float* wp9 = ws + (oc0 + j) * 144 + ic * 9;
            float s = fmaf(wp9[0], t[0], fmaf(wp9[1], t[1], fmaf(wp9[2], t[2],
                      fmaf(wp9[3], t[3], fmaf(wp9[4], t[4], fmaf(wp9[5], t[5],
                      fmaf(wp9[6], t[6], fmaf(wp9[7], t[7], wp9[8] * t[8]))))))));
            if (j == 0) a0 += s; else if (j == 1) a1 += s;
            else if (j == 2) a2 += s; else a3 += s;
        }
    }

    float* xp = xpad + ((size_t)(b * C + oc0) * XR + (h + 9)) * XS + (px + 9);
    float v;
    v = a0 + bs[oc0 + 0]; xp[0]       = 0.5f * v * (1.0f + erff(v * 0.70710678f));
    v = a1 + bs[oc0 + 1]; xp[XCH]     = 0.5f * v * (1.0f + erff(v * 0.70710678f));
    v = a2 + bs[oc0 + 2]; xp[2 * XCH] = 0.5f * v * (1.0f + erff(v * 0.70710678f));
    v = a3 + bs[oc0 + 3]; xp[3 * XCH] = 0.5f * v * (1.0f + erff(v * 0.70710678f));
}

// ===========================================================================
// conv2 (FROZEN r20): one block per (h,b), LDS tile staged once.
// ===========================================================================
__global__ __launch_bounds__(512) void conv2_sig(
    const float* __restrict__ ypad, const float* __restrict__ w2,
    const float* __restrict__ b2, float* __restrict__ out)
{
    __shared__ float ws[2304];
    __shared__ float bs[16];
    __shared__ __align__(16) float ys[16][3][136];   // 26.1 KB

    int tid = threadIdx.x;
    for (int i = tid; i < 2304; i += 512) ws[i] = w2[i];
    if (tid < 16) bs[tid] = b2[tid];

    int px  = tid & 127;
    int ocg = tid >> 7;
    int blk = blockIdx.x;                // 256 = h128 x b2
    int h   = blk & 127;
    int b   = blk >> 7;
    int oc0 = ocg * 4;

    #pragma unroll
    for (int j = 0; j < 4; ++j) {
        int m = tid + j * 512;
        if (m < 1632) {
            int ic = m / 102, rem = m - ic * 102, r = rem / 34, qq = rem % 34;
            float4 v = ld4(ypad + ((size_t)(b * C + ic) * YR + (h + r)) * YS + qq * 4);
            *(float4*)&ys[ic][r][qq * 4] = v;
        }
    }
    __syncthreads();

    float a0 = 0.f, a1 = 0.f, a2 = 0.f, a3 = 0.f;

    #pragma unroll 1
    for (int ic = 0; ic < 16; ++ic) {
        float t[9];
        #pragma unroll
        for (int r = 0; r < 3; ++r) {
            t[r * 3 + 0] = ys[ic][r][px + 3];
            t[r * 3 + 1] = ys[ic][r][px + 4];
            t[r * 3 + 2] = ys[ic][r][px + 5];
        }
        #pragma unroll
        for (int j = 0; j < 4; ++j) {
            const float* wp9 = ws + (oc0 + j) * 144 + ic * 9;
            float s = fmaf(wp9[0], t[0], fmaf(wp9[1], t[1], fmaf(wp9[2], t[2],
                      fmaf(wp9[3], t[3], fmaf(wp9[4], t[4], fmaf(wp9[5], t[5],
                      fmaf(wp9[6], t[6], fmaf(wp9[7], t[7], wp9[8] * t[8]))))))));
            if (j == 0) a0 += s; else if (j == 1) a1 += s;
            else if (j == 2) a2 += s; else a3 += s;
        }
    }

    float* op = out + ((size_t)(b * C + oc0) * H + h) * W + px;
    float v;
    v = a0 + bs[oc0 + 0]; op[0]      = 1.0f / (1.0f + expf(-v));
    v = a1 + bs[oc0 + 1]; op[HW]     = 1.0f / (1.0f + expf(-v));
    v = a2 + bs[oc0 + 2]; op[2 * HW] = 1.0f / (1.0f + expf(-v));
    v = a3 + bs[oc0 + 3]; op[3 * HW] = 1.0f / (1.0f + expf(-v));
}

// ---------------------------------------------------------------------------
extern "C" void kernel_launch(void* const* d_in, const int* in_sizes, int n_in,
                              void* d_out, int out_size, void* d_ws, size_t ws_size,
                              hipStream_t stream)
{
    const float* input  = (const float*)d_in[0];
    const float* kernel = (const float*)d_in[1];
    const float* w1     = (const float*)d_in[2];
    const float* b1     = (const float*)d_in[3];
    const float* w2     = (const float*)d_in[4];
    const float* b2     = (const float*)d_in[5];
    float* out = (float*)d_out;

    float* xpad = (float*)d_ws;
    float* ypad = xpad + XPAD_ELEMS;

    conv1_gelu<<<256, 512, 0, stream>>>(input, w1, b1, xpad);
    kpn19<<<512, 1024, 0, stream>>>(xpad, kernel, ypad);
    conv2_sig<<<256, 512, 0, stream>>>(ypad, w2, b2, out);
}

// Round 22
// 49.670 us; speedup vs baseline: 2.4435x; 2.4435x over previous
//
#include <hip/hip_runtime.h>
#include <math.h>

constexpr int B = 2, C = 16, H = 128, W = 128;
constexpr int HW = H * W;

// xpad: [B,16,146,148]; orig (h,w) -> (h+9, w+9); pads zeroed by conv1
constexpr int XR = 146, XS = 148, XCH = XR * XS;
constexpr size_t XPAD_ELEMS = (size_t)B * C * XCH;

// ypad: [B,16,130,136]; orig (h,w) -> (h+1, w+4); pads zeroed by kpn19
constexpr int YR = 130, YS = 136, YCH = YR * YS;

__device__ __forceinline__ float4 ld4(const float* p) { return *(const float4*)p; }

// ===========================================================================
// kpn19 (FROZEN r16/r20 exact — best measured; 3 restructures all regressed):
// q-split + kv[19] VMEM kern batch + LDS x-staging, vmcnt(0)+syncthreads/row.
// ===========================================================================
__global__ __launch_bounds__(1024) void kpn19(
    const float* __restrict__ xpad,  // [B,16,146,148]
    const float* __restrict__ kern,  // [B,361,128,128]
    float* __restrict__ ypad)        // [B,16,130,136]
{
    __shared__ __align__(16) float xls[4][2][16][84];   // 43,008 B
    __shared__ float red[3][16][64];                    // 12,288 B

    int tid  = threadIdx.x;
    int lane = tid & 63;
    int wq   = (tid >> 6) & 3;       // wave within q == channel group
    int q    = tid >> 8;             // kh-quarter, wave-uniform
    int blk  = blockIdx.x;           // 512 = wb2 x h128 x b2
    int wb   = blk & 1;
    int h    = (blk >> 1) & 127;
    int b    = blk >> 8;
    int px   = wb * 64 + lane;
    int c0   = wq * 4;

    // ---- ypad pad zeroing (replaces memset) ----
    if (tid < 64) {
        int pl = tid >> 2, i = tid & 3;
        int col = wb ? 132 + i : i;
        ypad[((size_t)(b * C + pl) * YR + (h + 1)) * YS + col] = 0.f;
    }
    if (h == 0 || h == 127) {
        int r = (h == 0) ? 0 : 129;
        for (int f = tid; f < 1088; f += 1024) {
            int pl = f / 68, col = wb * 68 + f % 68;
            ypad[((size_t)(b * C + pl) * YR + r) * YS + col] = 0.f;
        }
    }

    // ---- x staging sources: q-group covers 336 chunks = [16 ch][21 col4] ----
    int idx = tid & 255;
    int ma  = idx;
    int mb  = idx + 256;
    bool vb = (mb < 336);
    int ca  = ma / 21, cola = ma % 21;
    int cb  = vb ? mb / 21 : 0, colb = vb ? mb % 21 : 0;
    int kh0 = q * 5;
    int nkh = (q == 3) ? 4 : 5;

    const float* sa = xpad + (size_t)(b * C + ca) * XCH
                      + (size_t)(h + kh0) * XS + wb * 64 + cola * 4;
    const float* sb = xpad + (size_t)(b * C + cb) * XCH
                      + (size_t)(h + kh0) * XS + wb * 64 + colb * 4;

    const float* kp = kern + (size_t)b * 361 * HW + (size_t)h * W + px;

    float a0 = 0.f, a1 = 0.f, a2 = 0.f, a3 = 0.f;

#define STAGE(bufsel)                                                         \
    {                                                                         \
        __builtin_amdgcn_global_load_lds((const void*)sa,                     \
            (void*)(&xls[q][bufsel][0][0] + wq * 256), 16, 0, 0);             \
        if (vb)                                                               \
            __builtin_amdgcn_global_load_lds((const void*)sb,                 \
                (void*)(&xls[q][bufsel][0][0] + 1024 + wq * 256), 16, 0, 0);  \
        sa += XS; sb += XS;                                                   \
    }

    STAGE(0);
    asm volatile("s_waitcnt vmcnt(0)" ::: "memory");
    __syncthreads();

    #pragma unroll
    for (int r = 0; r < 5; ++r) {
        const int cur = r & 1;
        if (r + 1 < nkh) STAGE(cur ^ 1);
        if (r < nkh) {
            int kh = kh0 + r;
            float kv[19];
            const float* kpr = kp + (size_t)(kh * 19) * HW;
            #pragma unroll
            for (int kw = 0; kw < 19; ++kw)
                kv[kw] = kpr[(size_t)kw * HW];
            __builtin_amdgcn_sched_barrier(0);
            #pragma unroll
            for (int kw = 0; kw < 19; ++kw) {
                float k = kv[kw];
                a0 = fmaf(xls[q][cur][c0 + 0][lane + kw], k, a0);
                a1 = fmaf(xls[q][cur][c0 + 1][lane + kw], k, a1);
                a2 = fmaf(xls[q][cur][c0 + 2][lane + kw], k, a2);
                a3 = fmaf(xls[q][cur][c0 + 3][lane + kw], k, a3);
            }
        }
        asm volatile("s_waitcnt vmcnt(0)" ::: "memory");
        __syncthreads();
    }
#undef STAGE

    if (q > 0) {
        red[q - 1][c0 + 0][lane] = a0;
        red[q - 1][c0 + 1][lane] = a1;
        red[q - 1][c0 + 2][lane] = a2;
        red[q - 1][c0 + 3][lane] = a3;
    }
    __syncthreads();
    if (q == 0) {
        #pragma unroll
        for (int j = 0; j < 3; ++j) {
            a0 += red[j][c0 + 0][lane];
            a1 += red[j][c0 + 1][lane];
            a2 += red[j][c0 + 2][lane];
            a3 += red[j][c0 + 3][lane];
        }
        float* yp = ypad + ((size_t)(b * C + c0) * YR + (h + 1)) * YS + (px + 4);
        yp[0]       = a0;
        yp[YCH]     = a1;
        yp[2 * YCH] = a2;
        yp[3 * YCH] = a3;
    }
}

// ===========================================================================
// conv1: r20 skeleton + PADDED WEIGHT LAYOUT: ws[(oc*16+ic)*12 + k]
// (16B-aligned) so the 9 weights per (oc,ic) load as 2 ds_read_b128 + 1
// ds_read_b32 -> 12 weight-read instrs per ic for 4 oc (was 36). LDS instr
// count per ic: 45 -> 21.
// ===========================================================================
__global__ __launch_bounds__(512) void conv1_gelu(
    const float* __restrict__ in, const float* __restrict__ w1,
    const float* __restrict__ b1, float* __restrict__ xpad)
{
    __shared__ __align__(16) float ws[16 * 16 * 12];   // 12 KB, padded
    __shared__ float bs[16];
    __shared__ __align__(16) float xs[16][3][128];     // 24 KB

    int tid = threadIdx.x;
    for (int i = tid; i < 2304; i += 512) {
        int oi = i / 9, k = i % 9;                     // oi = oc*16+ic
        ws[oi * 12 + k] = w1[i];
    }
    if (tid < 16) bs[tid] = b1[tid];

    int px  = tid & 127;
    int ocg = tid >> 7;                  // 0..3, wave-uniform
    int blk = blockIdx.x;                // 256 = h128 x b2
    int h   = blk & 127;
    int b   = blk >> 7;
    int oc0 = ocg * 4;

    if (tid < 320) {
        int j = tid / 20, i = tid % 20;
        int col = (i < 9) ? i : 128 + i;
        xpad[((size_t)(b * C + j) * XR + (h + 9)) * XS + col] = 0.f;
    }
    if (h == 0 || h == 127) {
        int r0 = (h == 0) ? 0 : 137;
        for (int f = tid; f < 16 * 9 * XS; f += 512) {
            int j = f / (9 * XS), rem = f % (9 * XS);
            int r = r0 + rem / XS, col = rem % XS;
            xpad[((size_t)(b * C + j) * XR + r) * XS + col] = 0.f;
        }
    }

    const float4 z4 = make_float4(0.f, 0.f, 0.f, 0.f);
    #pragma unroll
    for (int j = 0; j < 3; ++j) {
        int m = tid + j * 512;           // < 1536 exactly
        int ic = m / 96, rem = m - ic * 96, r = rem >> 5, qq = rem & 31;
        int row = h + r - 1;
        float4 v = ((unsigned)row < 128u)
                 ? ld4(in + ((size_t)(b * C + ic) * H + row) * W + qq * 4) : z4;
        *(float4*)&xs[ic][r][qq * 4] = v;
    }
    __syncthreads();

    bool wm = (px > 0), wp = (px < 127);
    float a0 = 0.f, a1 = 0.f, a2 = 0.f, a3 = 0.f;

    #pragma unroll 1
    for (int ic = 0; ic < 16; ++ic) {
        float t[9];
        #pragma unroll
        for (int r = 0; r < 3; ++r) {
            t[r * 3 + 0] = wm ? xs[ic][r][px - 1] : 0.f;
            t[r * 3 + 1] = xs[ic][r][px];
            t[r * 3 + 2] = wp ? xs[ic][r][px + 1] : 0.f;
        }
        #pragma unroll
        for (int j = 0; j < 4; ++j) {
            const float* wp12 = ws + ((oc0 + j) * 16 + ic) * 12;
            float4 wA = ld4(wp12), wB = ld4(wp12 + 4);
            float  w8 = wp12[8];
            float s = fmaf(wA.x, t[0], fmaf(wA.y, t[1], fmaf(wA.z, t[2],
                      fmaf(wA.w, t[3], fmaf(wB.x, t[4], fmaf(wB.y, t[5],
                      fmaf(wB.z, t[6], fmaf(wB.w, t[7], w8 * t[8]))))))));
            if (j == 0) a0 += s; else if (j == 1) a1 += s;
            else if (j == 2) a2 += s; else a3 += s;
        }
    }

    float* xp = xpad + ((size_t)(b * C + oc0) * XR + (h + 9)) * XS + (px + 9);
    float v;
    v = a0 + bs[oc0 + 0]; xp[0]       = 0.5f * v * (1.0f + erff(v * 0.70710678f));
    v = a1 + bs[oc0 + 1]; xp[XCH]     = 0.5f * v * (1.0f + erff(v * 0.70710678f));
    v = a2 + bs[oc0 + 2]; xp[2 * XCH] = 0.5f * v * (1.0f + erff(v * 0.70710678f));
    v = a3 + bs[oc0 + 3]; xp[3 * XCH] = 0.5f * v * (1.0f + erff(v * 0.70710678f));
}

// ===========================================================================
// conv2: r20 skeleton + padded weight layout (same change as conv1).
// ===========================================================================
__global__ __launch_bounds__(512) void conv2_sig(
    const float* __restrict__ ypad, const float* __restrict__ w2,
    const float* __restrict__ b2, float* __restrict__ out)
{
    __shared__ __align__(16) float ws[16 * 16 * 12];   // 12 KB, padded
    __shared__ float bs[16];
    __shared__ __align__(16) float ys[16][3][136];     // 26.1 KB

    int tid = threadIdx.x;
    for (int i = tid; i < 2304; i += 512) {
        int oi = i / 9, k = i % 9;
        ws[oi * 12 + k] = w2[i];
    }
    if (tid < 16) bs[tid] = b2[tid];

    int px  = tid & 127;
    int ocg = tid >> 7;
    int blk = blockIdx.x;                // 256 = h128 x b2
    int h   = blk & 127;
    int b   = blk >> 7;
    int oc0 = ocg * 4;

    #pragma unroll
    for (int j = 0; j < 4; ++j) {
        int m = tid + j * 512;
        if (m < 1632) {
            int ic = m / 102, rem = m - ic * 102, r = rem / 34, qq = rem % 34;
            float4 v = ld4(ypad + ((size_t)(b * C + ic) * YR + (h + r)) * YS + qq * 4);
            *(float4*)&ys[ic][r][qq * 4] = v;
        }
    }
    __syncthreads();

    float a0 = 0.f, a1 = 0.f, a2 = 0.f, a3 = 0.f;

    #pragma unroll 1
    for (int ic = 0; ic < 16; ++ic) {
        float t[9];
        #pragma unroll
        for (int r = 0; r < 3; ++r) {
            t[r * 3 + 0] = ys[ic][r][px + 3];
            t[r * 3 + 1] = ys[ic][r][px + 4];
            t[r * 3 + 2] = ys[ic][r][px + 5];
        }
        #pragma unroll
        for (int j = 0; j < 4; ++j) {
            const float* wp12 = ws + ((oc0 + j) * 16 + ic) * 12;
            float4 wA = ld4(wp12), wB = ld4(wp12 + 4);
            float  w8 = wp12[8];
            float s = fmaf(wA.x, t[0], fmaf(wA.y, t[1], fmaf(wA.z, t[2],
                      fmaf(wA.w, t[3], fmaf(wB.x, t[4], fmaf(wB.y, t[5],
                      fmaf(wB.z, t[6], fmaf(wB.w, t[7], w8 * t[8]))))))));
            if (j == 0) a0 += s; else if (j == 1) a1 += s;
            else if (j == 2) a2 += s; else a3 += s;
        }
    }

    float* op = out + ((size_t)(b * C + oc0) * H + h) * W + px;
    float v;
    v = a0 + bs[oc0 + 0]; op[0]      = 1.0f / (1.0f + expf(-v));
    v = a1 + bs[oc0 + 1]; op[HW]     = 1.0f / (1.0f + expf(-v));
    v = a2 + bs[oc0 + 2]; op[2 * HW] = 1.0f / (1.0f + expf(-v));
    v = a3 + bs[oc0 + 3]; op[3 * HW] = 1.0f / (1.0f + expf(-v));
}

// ---------------------------------------------------------------------------
extern "C" void kernel_launch(void* const* d_in, const int* in_sizes, int n_in,
                              void* d_out, int out_size, void* d_ws, size_t ws_size,
                              hipStream_t stream)
{
    const float* input  = (const float*)d_in[0];
    const float* kernel = (const float*)d_in[1];
    const float* w1     = (const float*)d_in[2];
    const float* b1     = (const float*)d_in[3];
    const float* w2     = (const float*)d_in[4];
    const float* b2     = (const float*)d_in[5];
    float* out = (float*)d_out;

    float* xpad = (float*)d_ws;
    float* ypad = xpad + XPAD_ELEMS;

    conv1_gelu<<<256, 512, 0, stream>>>(input, w1, b1, xpad);
    kpn19<<<512, 1024, 0, stream>>>(xpad, kernel, ypad);
    conv2_sig<<<256, 512, 0, stream>>>(ypad, w2, b2, out);
}

// Round 23
// 48.067 us; speedup vs baseline: 2.5250x; 1.0333x over previous
//
#include <hip/hip_runtime.h>
#include <math.h>

constexpr int B = 2, C = 16, H = 128, W = 128;
constexpr int HW = H * W;

// xpad: [B,16,146,148]; orig (h,w) -> (h+9, w+9); pads zeroed by conv1
constexpr int XR = 146, XS = 148, XCH = XR * XS;
constexpr size_t XPAD_ELEMS = (size_t)B * C * XCH;

// ypad: [B,16,130,136]; orig (h,w) -> (h+1, w+4); pads zeroed by kpn19
constexpr int YR = 130, YS = 136, YCH = YR * YS;

__device__ __forceinline__ float4 ld4(const float* p) { return *(const float4*)p; }

// ===========================================================================
// kpn19 (FROZEN r16/r20/r22 exact — best measured):
// q-split + kv[19] VMEM kern batch + LDS x-staging, vmcnt(0)+syncthreads/row.
// ===========================================================================
__global__ __launch_bounds__(1024) void kpn19(
    const float* __restrict__ xpad,  // [B,16,146,148]
    const float* __restrict__ kern,  // [B,361,128,128]
    float* __restrict__ ypad)        // [B,16,130,136]
{
    __shared__ __align__(16) float xls[4][2][16][84];   // 43,008 B
    __shared__ float red[3][16][64];                    // 12,288 B

    int tid  = threadIdx.x;
    int lane = tid & 63;
    int wq   = (tid >> 6) & 3;       // wave within q == channel group
    int q    = tid >> 8;             // kh-quarter, wave-uniform
    int blk  = blockIdx.x;           // 512 = wb2 x h128 x b2
    int wb   = blk & 1;
    int h    = (blk >> 1) & 127;
    int b    = blk >> 8;
    int px   = wb * 64 + lane;
    int c0   = wq * 4;

    // ---- ypad pad zeroing (replaces memset) ----
    if (tid < 64) {
        int pl = tid >> 2, i = tid & 3;
        int col = wb ? 132 + i : i;
        ypad[((size_t)(b * C + pl) * YR + (h + 1)) * YS + col] = 0.f;
    }
    if (h == 0 || h == 127) {
        int r = (h == 0) ? 0 : 129;
        for (int f = tid; f < 1088; f += 1024) {
            int pl = f / 68, col = wb * 68 + f % 68;
            ypad[((size_t)(b * C + pl) * YR + r) * YS + col] = 0.f;
        }
    }

    // ---- x staging sources: q-group covers 336 chunks = [16 ch][21 col4] ----
    int idx = tid & 255;
    int ma  = idx;
    int mb  = idx + 256;
    bool vb = (mb < 336);
    int ca  = ma / 21, cola = ma % 21;
    int cb  = vb ? mb / 21 : 0, colb = vb ? mb % 21 : 0;
    int kh0 = q * 5;
    int nkh = (q == 3) ? 4 : 5;

    const float* sa = xpad + (size_t)(b * C + ca) * XCH
                      + (size_t)(h + kh0) * XS + wb * 64 + cola * 4;
    const float* sb = xpad + (size_t)(b * C + cb) * XCH
                      + (size_t)(h + kh0) * XS + wb * 64 + colb * 4;

    const float* kp = kern + (size_t)b * 361 * HW + (size_t)h * W + px;

    float a0 = 0.f, a1 = 0.f, a2 = 0.f, a3 = 0.f;

#define STAGE(bufsel)                                                         \
    {                                                                         \
        __builtin_amdgcn_global_load_lds((const void*)sa,                     \
            (void*)(&xls[q][bufsel][0][0] + wq * 256), 16, 0, 0);             \
        if (vb)                                                               \
            __builtin_amdgcn_global_load_lds((const void*)sb,                 \
                (void*)(&xls[q][bufsel][0][0] + 1024 + wq * 256), 16, 0, 0);  \
        sa += XS; sb += XS;                                                   \
    }

    STAGE(0);
    asm volatile("s_waitcnt vmcnt(0)" ::: "memory");
    __syncthreads();

    #pragma unroll
    for (int r = 0; r < 5; ++r) {
        const int cur = r & 1;
        if (r + 1 < nkh) STAGE(cur ^ 1);
        if (r < nkh) {
            int kh = kh0 + r;
            float kv[19];
            const float* kpr = kp + (size_t)(kh * 19) * HW;
            #pragma unroll
            for (int kw = 0; kw < 19; ++kw)
                kv[kw] = kpr[(size_t)kw * HW];
            __builtin_amdgcn_sched_barrier(0);
            #pragma unroll
            for (int kw = 0; kw < 19; ++kw) {
                float k = kv[kw];
                a0 = fmaf(xls[q][cur][c0 + 0][lane + kw], k, a0);
                a1 = fmaf(xls[q][cur][c0 + 1][lane + kw], k, a1);
                a2 = fmaf(xls[q][cur][c0 + 2][lane + kw], k, a2);
                a3 = fmaf(xls[q][cur][c0 + 3][lane + kw], k, a3);
            }
        }
        asm volatile("s_waitcnt vmcnt(0)" ::: "memory");
        __syncthreads();
    }
#undef STAGE

    if (q > 0) {
        red[q - 1][c0 + 0][lane] = a0;
        red[q - 1][c0 + 1][lane] = a1;
        red[q - 1][c0 + 2][lane] = a2;
        red[q - 1][c0 + 3][lane] = a3;
    }
    __syncthreads();
    if (q == 0) {
        #pragma unroll
        for (int j = 0; j < 3; ++j) {
            a0 += red[j][c0 + 0][lane];
            a1 += red[j][c0 + 1][lane];
            a2 += red[j][c0 + 2][lane];
            a3 += red[j][c0 + 3][lane];
        }
        float* yp = ypad + ((size_t)(b * C + c0) * YR + (h + 1)) * YS + (px + 4);
        yp[0]       = a0;
        yp[YCH]     = a1;
        yp[2 * YCH] = a2;
        yp[3 * YCH] = a3;
    }
}

// ===========================================================================
// conv1: r22 skeleton, weights moved OFF the LDS pipe onto the scalar/SMEM
// path: oc0 made provably wave-uniform via readfirstlane, weights+bias read
// directly from global w1/b1 (uniform address -> s_load, L1/K$-cached).
// Per-ic LDS instrs: 21 -> 9 (taps only); FMA-bound now. No ws staging.
// ===========================================================================
__global__ __launch_bounds__(512) void conv1_gelu(
    const float* __restrict__ in, const float* __restrict__ w1,
    const float* __restrict__ b1, float* __restrict__ xpad)
{
    __shared__ __align__(16) float xs[16][3][128];     // 24 KB

    int tid = threadIdx.x;
    int px  = tid & 127;
    int ocg = tid >> 7;                  // 0..3, wave-uniform
    int blk = blockIdx.x;                // 256 = h128 x b2
    int h   = blk & 127;
    int b   = blk >> 7;
    int oc0 = __builtin_amdgcn_readfirstlane(ocg * 4);  // provably uniform

    if (tid < 320) {
        int j = tid / 20, i = tid % 20;
        int col = (i < 9) ? i : 128 + i;
        xpad[((size_t)(b * C + j) * XR + (h + 9)) * XS + col] = 0.f;
    }
    if (h == 0 || h == 127) {
        int r0 = (h == 0) ? 0 : 137;
        for (int f = tid; f < 16 * 9 * XS; f += 512) {
            int j = f / (9 * XS), rem = f % (9 * XS);
            int r = r0 + rem / XS, col = rem % XS;
            xpad[((size_t)(b * C + j) * XR + r) * XS + col] = 0.f;
        }
    }

    const float4 z4 = make_float4(0.f, 0.f, 0.f, 0.f);
    #pragma unroll
    for (int j = 0; j < 3; ++j) {
        int m = tid + j * 512;           // < 1536 exactly
        int ic = m / 96, rem = m - ic * 96, r = rem >> 5, qq = rem & 31;
        int row = h + r - 1;
        float4 v = ((unsigned)row < 128u)
                 ? ld4(in + ((size_t)(b * C + ic) * H + row) * W + qq * 4) : z4;
        *(float4*)&xs[ic][r][qq * 4] = v;
    }
    __syncthreads();

    const float* wb = w1 + oc0 * 144;    // uniform base -> scalar loads
    bool wm = (px > 0), wp = (px < 127);
    float a0 = 0.f, a1 = 0.f, a2 = 0.f, a3 = 0.f;

    #pragma unroll 1
    for (int ic = 0; ic < 16; ++ic) {
        float t[9];
        #pragma unroll
        for (int r = 0; r < 3; ++r) {
            t[r * 3 + 0] = wm ? xs[ic][r][px - 1] : 0.f;
            t[r * 3 + 1] = xs[ic][r][px];
            t[r * 3 + 2] = wp ? xs[ic][r][px + 1] : 0.f;
        }
        #pragma unroll
        for (int j = 0; j < 4; ++j) {
            const float* wp9 = wb + j * 144 + ic * 9;   // uniform -> s_load
            float s = fmaf(wp9[0], t[0], fmaf(wp9[1], t[1], fmaf(wp9[2], t[2],
                      fmaf(wp9[3], t[3], fmaf(wp9[4], t[4], fmaf(wp9[5], t[5],
                      fmaf(wp9[6], t[6], fmaf(wp9[7], t[7], wp9[8] * t[8]))))))));
            if (j == 0) a0 += s; else if (j == 1) a1 += s;
            else if (j == 2) a2 += s; else a3 += s;
        }
    }

    float* xp = xpad + ((size_t)(b * C + oc0) * XR + (h + 9)) * XS + (px + 9);
    float v;
    v = a0 + b1[oc0 + 0]; xp[0]       = 0.5f * v * (1.0f + erff(v * 0.70710678f));
    v = a1 + b1[oc0 + 1]; xp[XCH]     = 0.5f * v * (1.0f + erff(v * 0.70710678f));
    v = a2 + b1[oc0 + 2]; xp[2 * XCH] = 0.5f * v * (1.0f + erff(v * 0.70710678f));
    v = a3 + b1[oc0 + 3]; xp[3 * XCH] = 0.5f * v * (1.0f + erff(v * 0.70710678f));
}

// ===========================================================================
// conv2: same scalar-pipe weight change.
// ===========================================================================
__global__ __launch_bounds__(512) void conv2_sig(
    const float* __restrict__ ypad, const float* __restrict__ w2,
    const float* __restrict__ b2, float* __restrict__ out)
{
    __shared__ __align__(16) float ys[16][3][136];     // 26.1 KB

    int tid = threadIdx.x;
    int px  = tid & 127;
    int ocg = tid >> 7;
    int blk = blockIdx.x;                // 256 = h128 x b2
    int h   = blk & 127;
    int b   = blk >> 7;
    int oc0 = __builtin_amdgcn_readfirstlane(ocg * 4);

    #pragma unroll
    for (int j = 0; j < 4; ++j) {
        int m = tid + j * 512;
        if (m < 1632) {
            int ic = m / 102, rem = m - ic * 102, r = rem / 34, qq = rem % 34;
            float4 v = ld4(ypad + ((size_t)(b * C + ic) * YR + (h + r)) * YS + qq * 4);
            *(float4*)&ys[ic][r][qq * 4] = v;
        }
    }
    __syncthreads();

    const float* wb = w2 + oc0 * 144;
    float a0 = 0.f, a1 = 0.f, a2 = 0.f, a3 = 0.f;

    #pragma unroll 1
    for (int ic = 0; ic < 16; ++ic) {
        float t[9];
        #pragma unroll
        for (int r = 0; r < 3; ++r) {
            t[r * 3 + 0] = ys[ic][r][px + 3];
            t[r * 3 + 1] = ys[ic][r][px + 4];
            t[r * 3 + 2] = ys[ic][r][px + 5];
        }
        #pragma unroll
        for (int j = 0; j < 4; ++j) {
            const float* wp9 = wb + j * 144 + ic * 9;
            float s = fmaf(wp9[0], t[0], fmaf(wp9[1], t[1], fmaf(wp9[2], t[2],
                      fmaf(wp9[3], t[3], fmaf(wp9[4], t[4], fmaf(wp9[5], t[5],
                      fmaf(wp9[6], t[6], fmaf(wp9[7], t[7], wp9[8] * t[8]))))))));
            if (j == 0) a0 += s; else if (j == 1) a1 += s;
            else if (j == 2) a2 += s; else a3 += s;
        }
    }

    float* op = out + ((size_t)(b * C + oc0) * H + h) * W + px;
    float v;
    v = a0 + b2[oc0 + 0]; op[0]      = 1.0f / (1.0f + expf(-v));
    v = a1 + b2[oc0 + 1]; op[HW]     = 1.0f / (1.0f + expf(-v));
    v = a2 + b2[oc0 + 2]; op[2 * HW] = 1.0f / (1.0f + expf(-v));
    v = a3 + b2[oc0 + 3]; op[3 * HW] = 1.0f / (1.0f + expf(-v));
}

// ---------------------------------------------------------------------------
extern "C" void kernel_launch(void* const* d_in, const int* in_sizes, int n_in,
                              void* d_out, int out_size, void* d_ws, size_t ws_size,
                              hipStream_t stream)
{
    const float* input  = (const float*)d_in[0];
    const float* kernel = (const float*)d_in[1];
    const float* w1     = (const float*)d_in[2];
    const float* b1     = (const float*)d_in[3];
    const float* w2     = (const float*)d_in[4];
    const float* b2     = (const float*)d_in[5];
    float* out = (float*)d_out;

    float* xpad = (float*)d_ws;
    float* ypad = xpad + XPAD_ELEMS;

    conv1_gelu<<<256, 512, 0, stream>>>(input, w1, b1, xpad);
    kpn19<<<512, 1024, 0, stream>>>(xpad, kernel, ypad);
    conv2_sig<<<256, 512, 0, stream>>>(ypad, w2, b2, out);
}

// Round 24
// 47.694 us; speedup vs baseline: 2.5447x; 1.0078x over previous
//
#include <hip/hip_runtime.h>
#include <math.h>

constexpr int B = 2, C = 16, H = 128, W = 128;
constexpr int HW = H * W;

// xpad: [B,16,146,148]; orig (h,w) -> (h+9, w+9); pads zeroed by conv1
constexpr int XR = 146, XS = 148, XCH = XR * XS;
constexpr size_t XPAD_ELEMS = (size_t)B * C * XCH;

// ypad: [B,16,130,136]; orig (h,w) -> (h+1, w+4); pads zeroed by kpn19
constexpr int YR = 130, YS = 136, YCH = YR * YS;

__device__ __forceinline__ float4 ld4(const float* p) { return *(const float4*)p; }

// ===========================================================================
// kpn19 (FROZEN r16 exact — best measured; 4 restructures regressed):
// q-split + kv[19] VMEM kern batch + LDS x-staging, vmcnt(0)+syncthreads/row.
// ===========================================================================
__global__ __launch_bounds__(1024) void kpn19(
    const float* __restrict__ xpad,  // [B,16,146,148]
    const float* __restrict__ kern,  // [B,361,128,128]
    float* __restrict__ ypad)        // [B,16,130,136]
{
    __shared__ __align__(16) float xls[4][2][16][84];   // 43,008 B
    __shared__ float red[3][16][64];                    // 12,288 B

    int tid  = threadIdx.x;
    int lane = tid & 63;
    int wq   = (tid >> 6) & 3;       // wave within q == channel group
    int q    = tid >> 8;             // kh-quarter, wave-uniform
    int blk  = blockIdx.x;           // 512 = wb2 x h128 x b2
    int wb   = blk & 1;
    int h    = (blk >> 1) & 127;
    int b    = blk >> 8;
    int px   = wb * 64 + lane;
    int c0   = wq * 4;

    // ---- ypad pad zeroing (replaces memset) ----
    if (tid < 64) {
        int pl = tid >> 2, i = tid & 3;
        int col = wb ? 132 + i : i;
        ypad[((size_t)(b * C + pl) * YR + (h + 1)) * YS + col] = 0.f;
    }
    if (h == 0 || h == 127) {
        int r = (h == 0) ? 0 : 129;
        for (int f = tid; f < 1088; f += 1024) {
            int pl = f / 68, col = wb * 68 + f % 68;
            ypad[((size_t)(b * C + pl) * YR + r) * YS + col] = 0.f;
        }
    }

    // ---- x staging sources: q-group covers 336 chunks = [16 ch][21 col4] ----
    int idx = tid & 255;
    int ma  = idx;
    int mb  = idx + 256;
    bool vb = (mb < 336);
    int ca  = ma / 21, cola = ma % 21;
    int cb  = vb ? mb / 21 : 0, colb = vb ? mb % 21 : 0;
    int kh0 = q * 5;
    int nkh = (q == 3) ? 4 : 5;

    const float* sa = xpad + (size_t)(b * C + ca) * XCH
                      + (size_t)(h + kh0) * XS + wb * 64 + cola * 4;
    const float* sb = xpad + (size_t)(b * C + cb) * XCH
                      + (size_t)(h + kh0) * XS + wb * 64 + colb * 4;

    const float* kp = kern + (size_t)b * 361 * HW + (size_t)h * W + px;

    float a0 = 0.f, a1 = 0.f, a2 = 0.f, a3 = 0.f;

#define STAGE(bufsel)                                                         \
    {                                                                         \
        __builtin_amdgcn_global_load_lds((const void*)sa,                     \
            (void*)(&xls[q][bufsel][0][0] + wq * 256), 16, 0, 0);             \
        if (vb)                                                               \
            __builtin_amdgcn_global_load_lds((const void*)sb,                 \
                (void*)(&xls[q][bufsel][0][0] + 1024 + wq * 256), 16, 0, 0);  \
        sa += XS; sb += XS;                                                   \
    }

    STAGE(0);
    asm volatile("s_waitcnt vmcnt(0)" ::: "memory");
    __syncthreads();

    #pragma unroll
    for (int r = 0; r < 5; ++r) {
        const int cur = r & 1;
        if (r + 1 < nkh) STAGE(cur ^ 1);
        if (r < nkh) {
            int kh = kh0 + r;
            float kv[19];
            const float* kpr = kp + (size_t)(kh * 19) * HW;
            #pragma unroll
            for (int kw = 0; kw < 19; ++kw)
                kv[kw] = kpr[(size_t)kw * HW];
            __builtin_amdgcn_sched_barrier(0);
            #pragma unroll
            for (int kw = 0; kw < 19; ++kw) {
                float k = kv[kw];
                a0 = fmaf(xls[q][cur][c0 + 0][lane + kw], k, a0);
                a1 = fmaf(xls[q][cur][c0 + 1][lane + kw], k, a1);
                a2 = fmaf(xls[q][cur][c0 + 2][lane + kw], k, a2);
                a3 = fmaf(xls[q][cur][c0 + 3][lane + kw], k, a3);
            }
        }
        asm volatile("s_waitcnt vmcnt(0)" ::: "memory");
        __syncthreads();
    }
#undef STAGE

    if (q > 0) {
        red[q - 1][c0 + 0][lane] = a0;
        red[q - 1][c0 + 1][lane] = a1;
        red[q - 1][c0 + 2][lane] = a2;
        red[q - 1][c0 + 3][lane] = a3;
    }
    __syncthreads();
    if (q == 0) {
        #pragma unroll
        for (int j = 0; j < 3; ++j) {
            a0 += red[j][c0 + 0][lane];
            a1 += red[j][c0 + 1][lane];
            a2 += red[j][c0 + 2][lane];
            a3 += red[j][c0 + 3][lane];
        }
        float* yp = ypad + ((size_t)(b * C + c0) * YR + (h + 1)) * YS + (px + 4);
        yp[0]       = a0;
        yp[YCH]     = a1;
        yp[2 * YCH] = a2;
        yp[3 * YCH] = a3;
    }
}

// ===========================================================================
// conv1: r23 skeleton + ILP: #pragma unroll 2 on the ic loop (two t[9]
// LDS batches in flight) under __launch_bounds__(512, 2) (256-VGPR budget;
// grid = 1 block/CU so the raised budget costs no occupancy).
// ===========================================================================
__global__ __launch_bounds__(512, 2) void conv1_gelu(
    const float* __restrict__ in, const float* __restrict__ w1,
    const float* __restrict__ b1, float* __restrict__ xpad)
{
    __shared__ __align__(16) float xs[16][3][128];     // 24 KB

    int tid = threadIdx.x;
    int px  = tid & 127;
    int ocg = tid >> 7;                  // 0..3, wave-uniform
    int blk = blockIdx.x;                // 256 = h128 x b2
    int h   = blk & 127;
    int b   = blk >> 7;
    int oc0 = __builtin_amdgcn_readfirstlane(ocg * 4);  // provably uniform

    if (tid < 320) {
        int j = tid / 20, i = tid % 20;
        int col = (i < 9) ? i : 128 + i;
        xpad[((size_t)(b * C + j) * XR + (h + 9)) * XS + col] = 0.f;
    }
    if (h == 0 || h == 127) {
        int r0 = (h == 0) ? 0 : 137;
        for (int f = tid; f < 16 * 9 * XS; f += 512) {
            int j = f / (9 * XS), rem = f % (9 * XS);
            int r = r0 + rem / XS, col = rem % XS;
            xpad[((size_t)(b * C + j) * XR + r) * XS + col] = 0.f;
        }
    }

    const float4 z4 = make_float4(0.f, 0.f, 0.f, 0.f);
    #pragma unroll
    for (int j = 0; j < 3; ++j) {
        int m = tid + j * 512;           // < 1536 exactly
        int ic = m / 96, rem = m - ic * 96, r = rem >> 5, qq = rem & 31;
        int row = h + r - 1;
        float4 v = ((unsigned)row < 128u)
                 ? ld4(in + ((size_t)(b * C + ic) * H + row) * W + qq * 4) : z4;
        *(float4*)&xs[ic][r][qq * 4] = v;
    }
    __syncthreads();

    const float* wb = w1 + oc0 * 144;    // uniform base -> scalar loads
    bool wm = (px > 0), wp = (px < 127);
    float a0 = 0.f, a1 = 0.f, a2 = 0.f, a3 = 0.f;

    #pragma unroll 2
    for (int ic = 0; ic < 16; ++ic) {
        float t[9];
        #pragma unroll
        for (int r = 0; r < 3; ++r) {
            t[r * 3 + 0] = wm ? xs[ic][r][px - 1] : 0.f;
            t[r * 3 + 1] = xs[ic][r][px];
            t[r * 3 + 2] = wp ? xs[ic][r][px + 1] : 0.f;
        }
        #pragma unroll
        for (int j = 0; j < 4; ++j) {
            const float* wp9 = wb + j * 144 + ic * 9;   // uniform -> s_load
            float s = fmaf(wp9[0], t[0], fmaf(wp9[1], t[1], fmaf(wp9[2], t[2],
                      fmaf(wp9[3], t[3], fmaf(wp9[4], t[4], fmaf(wp9[5], t[5],
                      fmaf(wp9[6], t[6], fmaf(wp9[7], t[7], wp9[8] * t[8]))))))));
            if (j == 0) a0 += s; else if (j == 1) a1 += s;
            else if (j == 2) a2 += s; else a3 += s;
        }
    }

    float* xp = xpad + ((size_t)(b * C + oc0) * XR + (h + 9)) * XS + (px + 9);
    float v;
    v = a0 + b1[oc0 + 0]; xp[0]       = 0.5f * v * (1.0f + erff(v * 0.70710678f));
    v = a1 + b1[oc0 + 1]; xp[XCH]     = 0.5f * v * (1.0f + erff(v * 0.70710678f));
    v = a2 + b1[oc0 + 2]; xp[2 * XCH] = 0.5f * v * (1.0f + erff(v * 0.70710678f));
    v = a3 + b1[oc0 + 3]; xp[3 * XCH] = 0.5f * v * (1.0f + erff(v * 0.70710678f));
}

// ===========================================================================
// conv2: same ILP change as conv1.
// ===========================================================================
__global__ __launch_bounds__(512, 2) void conv2_sig(
    const float* __restrict__ ypad, const float* __restrict__ w2,
    const float* __restrict__ b2, float* __restrict__ out)
{
    __shared__ __align__(16) float ys[16][3][136];     // 26.1 KB

    int tid = threadIdx.x;
    int px  = tid & 127;
    int ocg = tid >> 7;
    int blk = blockIdx.x;                // 256 = h128 x b2
    int h   = blk & 127;
    int b   = blk >> 7;
    int oc0 = __builtin_amdgcn_readfirstlane(ocg * 4);

    #pragma unroll
    for (int j = 0; j < 4; ++j) {
        int m = tid + j * 512;
        if (m < 1632) {
            int ic = m / 102, rem = m - ic * 102, r = rem / 34, qq = rem % 34;
            float4 v = ld4(ypad + ((size_t)(b * C + ic) * YR + (h + r)) * YS + qq * 4);
            *(float4*)&ys[ic][r][qq * 4] = v;
        }
    }
    __syncthreads();

    const float* wb = w2 + oc0 * 144;
    float a0 = 0.f, a1 = 0.f, a2 = 0.f, a3 = 0.f;

    #pragma unroll 2
    for (int ic = 0; ic < 16; ++ic) {
        float t[9];
        #pragma unroll
        for (int r = 0; r < 3; ++r) {
            t[r * 3 + 0] = ys[ic][r][px + 3];
            t[r * 3 + 1] = ys[ic][r][px + 4];
            t[r * 3 + 2] = ys[ic][r][px + 5];
        }
        #pragma unroll
        for (int j = 0; j < 4; ++j) {
            const float* wp9 = wb + j * 144 + ic * 9;
            float s = fmaf(wp9[0], t[0], fmaf(wp9[1], t[1], fmaf(wp9[2], t[2],
                      fmaf(wp9[3], t[3], fmaf(wp9[4], t[4], fmaf(wp9[5], t[5],
                      fmaf(wp9[6], t[6], fmaf(wp9[7], t[7], wp9[8] * t[8]))))))));
            if (j == 0) a0 += s; else if (j == 1) a1 += s;
            else if (j == 2) a2 += s; else a3 += s;
        }
    }

    float* op = out + ((size_t)(b * C + oc0) * H + h) * W + px;
    float v;
    v = a0 + b2[oc0 + 0]; op[0]      = 1.0f / (1.0f + expf(-v));
    v = a1 + b2[oc0 + 1]; op[HW]     = 1.0f / (1.0f + expf(-v));
    v = a2 + b2[oc0 + 2]; op[2 * HW] = 1.0f / (1.0f + expf(-v));
    v = a3 + b2[oc0 + 3]; op[3 * HW] = 1.0f / (1.0f + expf(-v));
}

// ---------------------------------------------------------------------------
extern "C" void kernel_launch(void* const* d_in, const int* in_sizes, int n_in,
                              void* d_out, int out_size, void* d_ws, size_t ws_size,
                              hipStream_t stream)
{
    const float* input  = (const float*)d_in[0];
    const float* kernel = (const float*)d_in[1];
    const float* w1     = (const float*)d_in[2];
    const float* b1     = (const float*)d_in[3];
    const float* w2     = (const float*)d_in[4];
    const float* b2     = (const float*)d_in[5];
    float* out = (float*)d_out;

    float* xpad = (float*)d_ws;
    float* ypad = xpad + XPAD_ELEMS;

    conv1_gelu<<<256, 512, 0, stream>>>(input, w1, b1, xpad);
    kpn19<<<512, 1024, 0, stream>>>(xpad, kernel, ypad);
    conv2_sig<<<256, 512, 0, stream>>>(ypad, w2, b2, out);
}

// Round 25
// 45.563 us; speedup vs baseline: 2.6638x; 1.0468x over previous
//
#include <hip/hip_runtime.h>
#include <math.h>

constexpr int B = 2, C = 16, H = 128, W = 128;
constexpr int HW = H * W;

// xpad: [B,16,146,148]; orig (h,w) -> (h+9, w+9); pads zeroed by conv1
constexpr int XR = 146, XS = 148, XCH = XR * XS;
constexpr size_t XPAD_ELEMS = (size_t)B * C * XCH;

// ypad: [B,16,130,136]; orig (h,w) -> (h+1, w+4); pads zeroed by kpn19
constexpr int YR = 130, YS = 136, YCH = YR * YS;

__device__ __forceinline__ float4 ld4(const float* p) { return *(const float4*)p; }

// ===========================================================================
// kpn19 (FROZEN r16 exact — best measured; wide-read variants provably hit
// 8-way LDS bank conflicts given the gll-forced 84-float row stride, so the
// b32/16-consecutive-lane layout is the structural optimum here).
// ===========================================================================
__global__ __launch_bounds__(1024) void kpn19(
    const float* __restrict__ xpad,  // [B,16,146,148]
    const float* __restrict__ kern,  // [B,361,128,128]
    float* __restrict__ ypad)        // [B,16,130,136]
{
    __shared__ __align__(16) float xls[4][2][16][84];   // 43,008 B
    __shared__ float red[3][16][64];                    // 12,288 B

    int tid  = threadIdx.x;
    int lane = tid & 63;
    int wq   = (tid >> 6) & 3;       // wave within q == channel group
    int q    = tid >> 8;             // kh-quarter, wave-uniform
    int blk  = blockIdx.x;           // 512 = wb2 x h128 x b2
    int wb   = blk & 1;
    int h    = (blk >> 1) & 127;
    int b    = blk >> 8;
    int px   = wb * 64 + lane;
    int c0   = wq * 4;

    // ---- ypad pad zeroing (replaces memset) ----
    if (tid < 64) {
        int pl = tid >> 2, i = tid & 3;
        int col = wb ? 132 + i : i;
        ypad[((size_t)(b * C + pl) * YR + (h + 1)) * YS + col] = 0.f;
    }
    if (h == 0 || h == 127) {
        int r = (h == 0) ? 0 : 129;
        for (int f = tid; f < 1088; f += 1024) {
            int pl = f / 68, col = wb * 68 + f % 68;
            ypad[((size_t)(b * C + pl) * YR + r) * YS + col] = 0.f;
        }
    }

    // ---- x staging sources: q-group covers 336 chunks = [16 ch][21 col4] ----
    int idx = tid & 255;
    int ma  = idx;
    int mb  = idx + 256;
    bool vb = (mb < 336);
    int ca  = ma / 21, cola = ma % 21;
    int cb  = vb ? mb / 21 : 0, colb = vb ? mb % 21 : 0;
    int kh0 = q * 5;
    int nkh = (q == 3) ? 4 : 5;

    const float* sa = xpad + (size_t)(b * C + ca) * XCH
                      + (size_t)(h + kh0) * XS + wb * 64 + cola * 4;
    const float* sb = xpad + (size_t)(b * C + cb) * XCH
                      + (size_t)(h + kh0) * XS + wb * 64 + colb * 4;

    const float* kp = kern + (size_t)b * 361 * HW + (size_t)h * W + px;

    float a0 = 0.f, a1 = 0.f, a2 = 0.f, a3 = 0.f;

#define STAGE(bufsel)                                                         \
    {                                                                         \
        __builtin_amdgcn_global_load_lds((const void*)sa,                     \
            (void*)(&xls[q][bufsel][0][0] + wq * 256), 16, 0, 0);             \
        if (vb)                                                               \
            __builtin_amdgcn_global_load_lds((const void*)sb,                 \
                (void*)(&xls[q][bufsel][0][0] + 1024 + wq * 256), 16, 0, 0);  \
        sa += XS; sb += XS;                                                   \
    }

    STAGE(0);
    asm volatile("s_waitcnt vmcnt(0)" ::: "memory");
    __syncthreads();

    #pragma unroll
    for (int r = 0; r < 5; ++r) {
        const int cur = r & 1;
        if (r + 1 < nkh) STAGE(cur ^ 1);
        if (r < nkh) {
            int kh = kh0 + r;
            float kv[19];
            const float* kpr = kp + (size_t)(kh * 19) * HW;
            #pragma unroll
            for (int kw = 0; kw < 19; ++kw)
                kv[kw] = kpr[(size_t)kw * HW];
            __builtin_amdgcn_sched_barrier(0);
            #pragma unroll
            for (int kw = 0; kw < 19; ++kw) {
                float k = kv[kw];
                a0 = fmaf(xls[q][cur][c0 + 0][lane + kw], k, a0);
                a1 = fmaf(xls[q][cur][c0 + 1][lane + kw], k, a1);
                a2 = fmaf(xls[q][cur][c0 + 2][lane + kw], k, a2);
                a3 = fmaf(xls[q][cur][c0 + 3][lane + kw], k, a3);
            }
        }
        asm volatile("s_waitcnt vmcnt(0)" ::: "memory");
        __syncthreads();
    }
#undef STAGE

    if (q > 0) {
        red[q - 1][c0 + 0][lane] = a0;
        red[q - 1][c0 + 1][lane] = a1;
        red[q - 1][c0 + 2][lane] = a2;
        red[q - 1][c0 + 3][lane] = a3;
    }
    __syncthreads();
    if (q == 0) {
        #pragma unroll
        for (int j = 0; j < 3; ++j) {
            a0 += red[j][c0 + 0][lane];
            a1 += red[j][c0 + 1][lane];
            a2 += red[j][c0 + 2][lane];
            a3 += red[j][c0 + 3][lane];
        }
        float* yp = ypad + ((size_t)(b * C + c0) * YR + (h + 1)) * YS + (px + 4);
        yp[0]       = a0;
        yp[YCH]     = a1;
        yp[2 * YCH] = a2;
        yp[3 * YCH] = a3;
    }
}

// ===========================================================================
// conv1: r24 skeleton at 1024 threads (thread = 1 px x 2 oc) -> 16 waves =
// 4 waves/SIMD (2x latency hiding). Same one-shot staging, scalar-pipe
// weights, unroll 2. __launch_bounds__(1024,4) -> 128-VGPR budget.
// ===========================================================================
__global__ __launch_bounds__(1024, 4) void conv1_gelu(
    const float* __restrict__ in, const float* __restrict__ w1,
    const float* __restrict__ b1, float* __restrict__ xpad)
{
    __shared__ __align__(16) float xs[16][3][128];     // 24 KB

    int tid = threadIdx.x;
    int px  = tid & 127;
    int ocg = tid >> 7;                  // 0..7, wave-uniform
    int blk = blockIdx.x;                // 256 = h128 x b2
    int h   = blk & 127;
    int b   = blk >> 7;
    int oc0 = __builtin_amdgcn_readfirstlane(ocg * 2);  // provably uniform

    if (tid < 320) {
        int j = tid / 20, i = tid % 20;
        int col = (i < 9) ? i : 128 + i;
        xpad[((size_t)(b * C + j) * XR + (h + 9)) * XS + col] = 0.f;
    }
    if (h == 0 || h == 127) {
        int r0 = (h == 0) ? 0 : 137;
        for (int f = tid; f < 16 * 9 * XS; f += 1024) {
            int j = f / (9 * XS), rem = f % (9 * XS);
            int r = r0 + rem / XS, col = rem % XS;
            xpad[((size_t)(b * C + j) * XR + r) * XS + col] = 0.f;
        }
    }

    const float4 z4 = make_float4(0.f, 0.f, 0.f, 0.f);
    #pragma unroll
    for (int j = 0; j < 2; ++j) {
        int m = tid + j * 1024;          // < 1536
        if (m < 1536) {
            int ic = m / 96, rem = m - ic * 96, r = rem >> 5, qq = rem & 31;
            int row = h + r - 1;
            float4 v = ((unsigned)row < 128u)
                     ? ld4(in + ((size_t)(b * C + ic) * H + row) * W + qq * 4) : z4;
            *(float4*)&xs[ic][r][qq * 4] = v;
        }
    }
    __syncthreads();

    const float* wb = w1 + oc0 * 144;    // uniform base -> scalar loads
    bool wm = (px > 0), wp = (px < 127);
    float a0 = 0.f, a1 = 0.f;

    #pragma unroll 2
    for (int ic = 0; ic < 16; ++ic) {
        float t[9];
        #pragma unroll
        for (int r = 0; r < 3; ++r) {
            t[r * 3 + 0] = wm ? xs[ic][r][px - 1] : 0.f;
            t[r * 3 + 1] = xs[ic][r][px];
            t[r * 3 + 2] = wp ? xs[ic][r][px + 1] : 0.f;
        }
        #pragma unroll
        for (int j = 0; j < 2; ++j) {
            const float* wp9 = wb + j * 144 + ic * 9;   // uniform -> s_load
            float s = fmaf(wp9[0], t[0], fmaf(wp9[1], t[1], fmaf(wp9[2], t[2],
                      fmaf(wp9[3], t[3], fmaf(wp9[4], t[4], fmaf(wp9[5], t[5],
                      fmaf(wp9[6], t[6], fmaf(wp9[7], t[7], wp9[8] * t[8]))))))));
            if (j == 0) a0 += s; else a1 += s;
        }
    }

    float* xp = xpad + ((size_t)(b * C + oc0) * XR + (h + 9)) * XS + (px + 9);
    float v;
    v = a0 + b1[oc0 + 0]; xp[0]   = 0.5f * v * (1.0f + erff(v * 0.70710678f));
    v = a1 + b1[oc0 + 1]; xp[XCH] = 0.5f * v * (1.0f + erff(v * 0.70710678f));
}

// ===========================================================================
// conv2: same 1024-thread change.
// ===========================================================================
__global__ __launch_bounds__(1024, 4) void conv2_sig(
    const float* __restrict__ ypad, const float* __restrict__ w2,
    const float* __restrict__ b2, float* __restrict__ out)
{
    __shared__ __align__(16) float ys[16][3][136];     // 26.1 KB

    int tid = threadIdx.x;
    int px  = tid & 127;
    int ocg = tid >> 7;
    int blk = blockIdx.x;                // 256 = h128 x b2
    int h   = blk & 127;
    int b   = blk >> 7;
    int oc0 = __builtin_amdgcn_readfirstlane(ocg * 2);

    #pragma unroll
    for (int j = 0; j < 2; ++j) {
        int m = tid + j * 1024;
        if (m < 1632) {
            int ic = m / 102, rem = m - ic * 102, r = rem / 34, qq = rem % 34;
            float4 v = ld4(ypad + ((size_t)(b * C + ic) * YR + (h + r)) * YS + qq * 4);
            *(float4*)&ys[ic][r][qq * 4] = v;
        }
    }
    __syncthreads();

    const float* wb = w2 + oc0 * 144;
    float a0 = 0.f, a1 = 0.f;

    #pragma unroll 2
    for (int ic = 0; ic < 16; ++ic) {
        float t[9];
        #pragma unroll
        for (int r = 0; r < 3; ++r) {
            t[r * 3 + 0] = ys[ic][r][px + 3];
            t[r * 3 + 1] = ys[ic][r][px + 4];
            t[r * 3 + 2] = ys[ic][r][px + 5];
        }
        #pragma unroll
        for (int j = 0; j < 2; ++j) {
            const float* wp9 = wb + j * 144 + ic * 9;
            float s = fmaf(wp9[0], t[0], fmaf(wp9[1], t[1], fmaf(wp9[2], t[2],
                      fmaf(wp9[3], t[3], fmaf(wp9[4], t[4], fmaf(wp9[5], t[5],
                      fmaf(wp9[6], t[6], fmaf(wp9[7], t[7], wp9[8] * t[8]))))))));
            if (j == 0) a0 += s; else a1 += s;
        }
    }

    float* op = out + ((size_t)(b * C + oc0) * H + h) * W + px;
    float v;
    v = a0 + b2[oc0 + 0]; op[0]  = 1.0f / (1.0f + expf(-v));
    v = a1 + b2[oc0 + 1]; op[HW] = 1.0f / (1.0f + expf(-v));
}

// ---------------------------------------------------------------------------
extern "C" void kernel_launch(void* const* d_in, const int* in_sizes, int n_in,
                              void* d_out, int out_size, void* d_ws, size_t ws_size,
                              hipStream_t stream)
{
    const float* input  = (const float*)d_in[0];
    const float* kernel = (const float*)d_in[1];
    const float* w1     = (const float*)d_in[2];
    const float* b1     = (const float*)d_in[3];
    const float* w2     = (const float*)d_in[4];
    const float* b2     = (const float*)d_in[5];
    float* out = (float*)d_out;

    float* xpad = (float*)d_ws;
    float* ypad = xpad + XPAD_ELEMS;

    conv1_gelu<<<256, 1024, 0, stream>>>(input, w1, b1, xpad);
    kpn19<<<512, 1024, 0, stream>>>(xpad, kernel, ypad);
    conv2_sig<<<256, 1024, 0, stream>>>(ypad, w2, b2, out);
}